// Round 1
// baseline (189.909 us; speedup 1.0000x reference)
//
#include <hip/hip_runtime.h>

typedef short bf16x8 __attribute__((ext_vector_type(8)));
typedef float f32x4 __attribute__((ext_vector_type(4)));
typedef unsigned short u16;

#define NNODE 196608
#define FF 32
#define KK 9
#define COLS 256   // UP * OUT_FEATURES
#define KTOT 288   // KK * FF

__device__ __forceinline__ u16 f2bf(float f) {
    unsigned u = __builtin_bit_cast(unsigned, f);
    return (u16)((u + 0x7fffu + ((u >> 16) & 1u)) >> 16);  // RTNE
}

// prep 1: x f32 -> bf16, 8 elems/thread
__global__ void cvt_x(const float* __restrict__ x, u16* __restrict__ xb, int n8) {
    int i = blockIdx.x * blockDim.x + threadIdx.x;
    if (i >= n8) return;
    f32x4 v0 = *((const f32x4*)x + (size_t)i * 2);
    f32x4 v1 = *((const f32x4*)x + (size_t)i * 2 + 1);
    union { u16 h[8]; bf16x8 v; } r;
    #pragma unroll
    for (int j = 0; j < 4; ++j) r.h[j] = f2bf(v0[j]);
    #pragma unroll
    for (int j = 0; j < 4; ++j) r.h[4 + j] = f2bf(v1[j]);
    *((bf16x8*)xb + i) = r.v;
}

// prep 2: W (K,F,UP,O) f32 -> Wt bf16 [c=0..255][kf=0..287] (transposed)
__global__ void cvt_w(const float* __restrict__ W, u16* __restrict__ Wt) {
    int gid = blockIdx.x * 256 + threadIdx.x;   // 73728 total
    int c = gid / KTOT;
    int kf = gid - c * KTOT;
    Wt[gid] = f2bf(W[(size_t)kf * COLS + c]);
}

// main: wg = 128 rows x 256 cols; 4 waves, each wave 32 rows (2 M-tiles)
__global__ __launch_bounds__(256, 2) void updown_main(
    const u16* __restrict__ xb, const u16* __restrict__ Wt,
    const int* __restrict__ adjc, const float* __restrict__ bias,
    float* __restrict__ out)
{
    __shared__ __align__(16) u16 buf[2][COLS * FF];   // 2 x 16 KB
    const int tid  = threadIdx.x;
    const int w    = tid >> 6;
    const int lane = tid & 63;
    const int l15  = lane & 15;
    const int q    = lane >> 4;
    const int wrow = blockIdx.x * 128 + w * 32;
    const int t    = (wrow >= NNODE) ? 1 : 0;
    const int n0   = wrow - t * NNODE + l15;
    const int n1   = n0 + 16;
    const u16* xbt = xb + (size_t)t * NNODE * FF;

    int idx0[KK], idx1[KK];
    #pragma unroll
    for (int k = 0; k < KK; ++k) idx0[k] = adjc[n0 * 9 + k];
    #pragma unroll
    for (int k = 0; k < KK; ++k) idx1[k] = adjc[n1 * 9 + k];

    // register-stage W slice 0 (thread tid owns column c = tid: 64 B)
    const u16* wsrc = Wt + (size_t)tid * KTOT;
    bf16x8 r0 = *(const bf16x8*)(wsrc + 0);
    bf16x8 r1 = *(const bf16x8*)(wsrc + 8);
    bf16x8 r2 = *(const bf16x8*)(wsrc + 16);
    bf16x8 r3 = *(const bf16x8*)(wsrc + 24);

    // A fragments for step 0
    bf16x8 a0c = *(const bf16x8*)(xbt + (size_t)idx0[0] * FF + q * 8);
    bf16x8 a1c = *(const bf16x8*)(xbt + (size_t)idx1[0] * FF + q * 8);

    f32x4 acc0[16], acc1[16];
    #pragma unroll
    for (int nt = 0; nt < 16; ++nt) {
        acc0[nt] = (f32x4){0.f, 0.f, 0.f, 0.f};
        acc1[nt] = (f32x4){0.f, 0.f, 0.f, 0.f};
    }

    const int swz_w = (tid >> 1) & 3;   // bank-phase swizzle (writer, c = tid)
    const int swz_r = (l15 >> 1) & 3;   // same swizzle at read (c = nt*16+l15)

    #pragma unroll
    for (int kk = 0; kk < 9; ++kk) {
        // write staged slice kk into LDS (chunk index XOR-swizzled)
        u16* wb = &buf[kk & 1][0] + tid * FF;
        *(bf16x8*)(wb + (0 ^ swz_w) * 8) = r0;
        *(bf16x8*)(wb + (1 ^ swz_w) * 8) = r1;
        *(bf16x8*)(wb + (2 ^ swz_w) * 8) = r2;
        *(bf16x8*)(wb + (3 ^ swz_w) * 8) = r3;
        __syncthreads();

        bf16x8 a0n, a1n;
        if (kk < 8) {
            // prefetch next A fragments (random gather -> hide under MFMAs)
            a0n = *(const bf16x8*)(xbt + (size_t)idx0[kk + 1] * FF + q * 8);
            a1n = *(const bf16x8*)(xbt + (size_t)idx1[kk + 1] * FF + q * 8);
            // prefetch next W slice into regs (consumed at next ds_write)
            const u16* ws2 = wsrc + (kk + 1) * FF;
            r0 = *(const bf16x8*)(ws2 + 0);
            r1 = *(const bf16x8*)(ws2 + 8);
            r2 = *(const bf16x8*)(ws2 + 16);
            r3 = *(const bf16x8*)(ws2 + 24);
        }

        const u16* rb = &buf[kk & 1][0];
        const int qoff = (q ^ swz_r) * 8;
        #pragma unroll
        for (int nt = 0; nt < 16; ++nt) {
            bf16x8 bfrag = *(const bf16x8*)(rb + (nt * 16 + l15) * FF + qoff);
            acc0[nt] = __builtin_amdgcn_mfma_f32_16x16x32_bf16(a0c, bfrag, acc0[nt], 0, 0, 0);
            acc1[nt] = __builtin_amdgcn_mfma_f32_16x16x32_bf16(a1c, bfrag, acc1[nt], 0, 0, 0);
        }
        if (kk < 8) { a0c = a0n; a1c = a1n; }
    }

    // epilogue: bias + store (C/D layout: col = lane&15, row = (lane>>4)*4 + reg)
    float bb[16];
    #pragma unroll
    for (int nt = 0; nt < 16; ++nt) bb[nt] = bias[nt * 16 + l15];

    #pragma unroll
    for (int nt = 0; nt < 16; ++nt) {
        #pragma unroll
        for (int r = 0; r < 4; ++r) {
            const int row0 = wrow + q * 4 + r;
            out[(size_t)row0 * COLS + nt * 16 + l15]        = acc0[nt][r] + bb[nt];
            out[(size_t)(row0 + 16) * COLS + nt * 16 + l15] = acc1[nt][r] + bb[nt];
        }
    }
}

extern "C" void kernel_launch(void* const* d_in, const int* in_sizes, int n_in,
                              void* d_out, int out_size, void* d_ws, size_t ws_size,
                              hipStream_t stream) {
    const float* x    = (const float*)d_in[0];
    const int*   adjc = (const int*)d_in[1];
    const float* W    = (const float*)d_in[2];
    const float* b    = (const float*)d_in[3];
    float* out = (float*)d_out;

    u16* xb = (u16*)d_ws;                            // 2*196608*32 bf16 = 25.2 MB
    u16* Wt = xb + (size_t)2 * NNODE * FF;           // 256*288 bf16 = 147 KB

    cvt_x<<<dim3(6144), dim3(256), 0, stream>>>(x, xb, 1572864);
    cvt_w<<<dim3(288), dim3(256), 0, stream>>>(W, Wt);
    updown_main<<<dim3(3072), dim3(256), 0, stream>>>(xb, Wt, adjc, b, out);
}

// Round 2
// 156.190 us; speedup vs baseline: 1.2159x; 1.2159x over previous
//
#include <hip/hip_runtime.h>

typedef short bf16x8 __attribute__((ext_vector_type(8)));
typedef float f32x4 __attribute__((ext_vector_type(4)));
typedef unsigned short u16;

#define NNODE 196608
#define FF 32
#define KK 9
#define COLS 256   // UP * OUT_FEATURES
#define KTOT 288   // KK * FF
#define WELEMS (COLS * KTOT)   // 73728 elems = 144 KB bf16

__device__ __forceinline__ u16 f2bf(float f) {
    unsigned u = __builtin_bit_cast(unsigned, f);
    return (u16)((u + 0x7fffu + ((u >> 16) & 1u)) >> 16);  // RTNE
}

// prep 1: x f32 -> bf16, 8 elems/thread
__global__ void cvt_x(const float* __restrict__ x, u16* __restrict__ xb, int n8) {
    int i = blockIdx.x * blockDim.x + threadIdx.x;
    if (i >= n8) return;
    f32x4 v0 = *((const f32x4*)x + (size_t)i * 2);
    f32x4 v1 = *((const f32x4*)x + (size_t)i * 2 + 1);
    union { u16 h[8]; bf16x8 v; } r;
    #pragma unroll
    for (int j = 0; j < 4; ++j) r.h[j] = f2bf(v0[j]);
    #pragma unroll
    for (int j = 0; j < 4; ++j) r.h[4 + j] = f2bf(v1[j]);
    *((bf16x8*)xb + i) = r.v;
}

// prep 2: W (K,F,UP,O) f32 -> Wt bf16 [c=0..255][kf=0..287] (transposed)
__global__ void cvt_w(const float* __restrict__ W, u16* __restrict__ Wt) {
    int gid = blockIdx.x * 256 + threadIdx.x;   // 73728 total
    int c = gid / KTOT;
    int kf = gid - c * KTOT;
    Wt[gid] = f2bf(W[(size_t)kf * COLS + c]);
}

// main: 512 threads = 8 waves. Block tile 256 rows x 256 cols.
// Wave (wr = w>>1, wc = w&1): 64 rows x 128 cols. W fully LDS-resident,
// ONE barrier, barrier-free K-loop (9 steps of K=32).
__global__ __launch_bounds__(512, 2) void updown_main(
    const u16* __restrict__ xb, const u16* __restrict__ Wt,
    const int* __restrict__ adjc, const float* __restrict__ bias,
    float* __restrict__ out)
{
    __shared__ __align__(16) u16 wlds[WELEMS];   // 144 KB, read-only after load

    const int tid = threadIdx.x;

    // cooperative W copy: 18 iters x 8 KB, fully coalesced both sides, linear
    #pragma unroll
    for (int i = 0; i < 18; ++i) {
        *(bf16x8*)(wlds + i * 4096 + tid * 8) =
            *(const bf16x8*)(Wt + i * 4096 + tid * 8);
    }

    const int w    = tid >> 6;
    const int lane = tid & 63;
    const int l15  = lane & 15;
    const int q    = lane >> 4;
    const int wr   = w >> 1;            // 0..3
    const int wc   = w & 1;             // 0..1
    const int blk  = blockIdx.x;
    const int t    = (blk >= 768) ? 1 : 0;
    const int nb   = (blk - t * 768) * 256 + wr * 64;   // node base for this wave
    const int cb   = wc * 128;                          // col base
    const u16* xbt = xb + (size_t)t * NNODE * FF;

    // idx pipeline (2 deep) + A-gather pipeline (1 deep)
    int idxC[4], idxN[4];
    #pragma unroll
    for (int mt = 0; mt < 4; ++mt) idxC[mt] = adjc[(nb + mt * 16 + l15) * 9 + 0];
    #pragma unroll
    for (int mt = 0; mt < 4; ++mt) idxN[mt] = adjc[(nb + mt * 16 + l15) * 9 + 1];

    bf16x8 aC[4], aN[4];
    #pragma unroll
    for (int mt = 0; mt < 4; ++mt)
        aC[mt] = *(const bf16x8*)(xbt + (size_t)idxC[mt] * FF + q * 8);

    f32x4 acc[4][8];
    #pragma unroll
    for (int mt = 0; mt < 4; ++mt)
        #pragma unroll
        for (int nt = 0; nt < 8; ++nt)
            acc[mt][nt] = (f32x4){0.f, 0.f, 0.f, 0.f};

    __syncthreads();   // W resident; no further barriers

    // per-lane LDS base (bytes -> elem index): col (cb+l15), k-offset q*8
    const u16* bbase = wlds + (cb + l15) * KTOT + q * 8;

    #pragma unroll
    for (int kk = 0; kk < 9; ++kk) {
        if (kk < 8) {
            // gather A for step kk+1 (uses idxN), then refill idx for kk+2
            #pragma unroll
            for (int mt = 0; mt < 4; ++mt)
                aN[mt] = *(const bf16x8*)(xbt + (size_t)idxN[mt] * FF + q * 8);
            if (kk < 7) {
                #pragma unroll
                for (int mt = 0; mt < 4; ++mt)
                    idxN[mt] = adjc[(nb + mt * 16 + l15) * 9 + (kk + 2)];
            }
        }

        bf16x8 bf[8];
        #pragma unroll
        for (int nt = 0; nt < 8; ++nt)
            bf[nt] = *(const bf16x8*)(bbase + nt * 16 * KTOT + kk * 32);

        #pragma unroll
        for (int nt = 0; nt < 8; ++nt)
            #pragma unroll
            for (int mt = 0; mt < 4; ++mt)
                acc[mt][nt] = __builtin_amdgcn_mfma_f32_16x16x32_bf16(
                    aC[mt], bf[nt], acc[mt][nt], 0, 0, 0);

        if (kk < 8) {
            #pragma unroll
            for (int mt = 0; mt < 4; ++mt) aC[mt] = aN[mt];
        }
    }

    // epilogue: bias + store (C/D: col = lane&15, row = q*4 + reg)
    float bb[8];
    #pragma unroll
    for (int nt = 0; nt < 8; ++nt) bb[nt] = bias[cb + nt * 16 + l15];

    const size_t rowbase = (size_t)t * NNODE + nb;
    #pragma unroll
    for (int mt = 0; mt < 4; ++mt) {
        #pragma unroll
        for (int nt = 0; nt < 8; ++nt) {
            #pragma unroll
            for (int r = 0; r < 4; ++r) {
                out[(rowbase + mt * 16 + q * 4 + r) * COLS + cb + nt * 16 + l15]
                    = acc[mt][nt][r] + bb[nt];
            }
        }
    }
}

extern "C" void kernel_launch(void* const* d_in, const int* in_sizes, int n_in,
                              void* d_out, int out_size, void* d_ws, size_t ws_size,
                              hipStream_t stream) {
    const float* x    = (const float*)d_in[0];
    const int*   adjc = (const int*)d_in[1];
    const float* W    = (const float*)d_in[2];
    const float* b    = (const float*)d_in[3];
    float* out = (float*)d_out;

    u16* xb = (u16*)d_ws;                            // 2*196608*32 bf16 = 25.2 MB
    u16* Wt = xb + (size_t)2 * NNODE * FF;           // 73728 bf16 = 144 KB

    cvt_x<<<dim3(6144), dim3(256), 0, stream>>>(x, xb, 1572864);
    cvt_w<<<dim3(288), dim3(256), 0, stream>>>(W, Wt);
    updown_main<<<dim3(1536), dim3(512), 0, stream>>>(xb, Wt, adjc, b, out);
}